// Round 8
// baseline (5841.380 us; speedup 1.0000x reference)
//
#include <hip/hip_runtime.h>

typedef unsigned int u32;
typedef unsigned short u16;
typedef float f32x2 __attribute__((ext_vector_type(2)));

constexpr int NIN = 10, H = 100, OUTN = 10, NL = 5, NB = 64, T = 2048;

__device__ __forceinline__ float ftanh(float x){
  float e = __expf(x + x);
  return 1.0f - 2.0f/(e + 1.0f);
}

// Two blocks per batch row (grid 128): block b = layers 0..2, block b+64 =
// layers 3..4 + out. Full fp32 (bf16/fp16 state saturates at ~5e-2 absmax).
// R4 VGPR=84 (=512/6), R5 VGPR=60 (=512/8), R7 VGPR=80: the allocator was
// SPILLING TO HIT ITS DEFAULT MAX-OCCUPANCY TARGET — not a liveness problem.
// Fix: amdgpu_waves_per_eu(3,3) pins the target to the true occupancy
// (10 waves on 4 EUs = {3,3,2,2}) -> VGPR budget 512/3 = 170 >= ~150 needed.
__global__ __launch_bounds__(640)
__attribute__((amdgpu_waves_per_eu(3, 3)))
void rnn5(const float* __restrict__ xg, const float* __restrict__ hprev,
          const float* __restrict__ Wih0, const float* __restrict__ Wih,
          const float* __restrict__ Whh, const float* __restrict__ bih,
          const float* __restrict__ bhh, const float* __restrict__ Wout,
          const float* __restrict__ bout, float* __restrict__ outf,
          float* __restrict__ ring, int* __restrict__ flags, int ringSlots)
{
  __shared__ __align__(16) float hb[3][2][128];   // A: h0,h1,h2 ; B: h3,h4
  __shared__ __align__(16) float part[2][128];    // ih partials
  __shared__ __align__(16) float h2l[2][112];     // B: staged h2
  __shared__ __align__(16) float xst[2][12];      // A: staged x[t]

  const int tid = threadIdx.x, wv = tid>>6, lane = tid&63;
  const bool isA = (blockIdx.x < NB);
  const int b = isA ? (int)blockIdx.x : (int)blockIdx.x - NB;
  const int rmask = ringSlots - 1;
  int* progp = flags + b*32;            // h2 ready-count (A publishes)
  int* consp = flags + NB*32 + b*32;    // h2 consumed-count (B publishes)
  const int row = ((wv&1)?64:0) + lane;

  // ---- role setup ----------------------------------------------------------
  f32x2 P0={0,0},P1=P0,P2=P0,P3=P0,P4=P0,P5=P0,P6=P0,P7=P0,P8=P0,P9=P0,
        P10=P0,P11=P0,P12=P0,P13=P0,P14=P0,P15=P0,P16=P0,P17=P0,P18=P0,P19=P0,
        P20=P0,P21=P0,P22=P0,P23=P0,P24=P0,P25=P0,P26=P0,P27=P0,P28=P0,P29=P0,
        P30=P0,P31=P0,P32=P0,P33=P0,P34=P0,P35=P0,P36=P0,P37=P0,P38=P0,P39=P0,
        P40=P0,P41=P0,P42=P0,P43=P0,P44=P0,P45=P0,P46=P0,P47=P0,P48=P0,P49=P0;
  f32x2 U0={0,0},U1=U0,U2=U0,U3=U0,U4=U0;
  float bias = 0.f;
  int dt = 1<<20, srcL = 0, partIdx = -1, dstL = 0;
  bool srcH2=false, hh=false, hasX=false, ringSt=false, isOut=false;
  const f32x2* wsrc = nullptr;
  const f32x2* usrc = nullptr;

  if (isA){
    if (wv<2){            // L0 hh + x
      dt=0; hh=true; dstL=0; srcL=0; hasX=true;
      if (row<H){
        wsrc = (const f32x2*)(Whh + (size_t)row*H);
        usrc = (const f32x2*)(Wih0 + (size_t)row*NIN);
        bias = bih[row] + bhh[row];
      }
    } else if (wv<4){     // L1 ih (Wih[0])
      dt=1; srcL=0; partIdx=0;
      if (row<H) wsrc = (const f32x2*)(Wih + (size_t)row*H);
    } else if (wv<6){     // L1 hh
      dt=1; hh=true; dstL=1; srcL=1; partIdx=0;
      if (row<H){
        wsrc = (const f32x2*)(Whh + (size_t)1*H*H + (size_t)row*H);
        bias = bih[1*H+row] + bhh[1*H+row];
      }
    } else if (wv<8){     // L2 ih (Wih[1])
      dt=2; srcL=1; partIdx=1;
      if (row<H) wsrc = (const f32x2*)(Wih + (size_t)1*H*H + (size_t)row*H);
    } else {              // L2 hh + ring store
      dt=2; hh=true; dstL=2; srcL=2; partIdx=1; ringSt=true;
      if (row<H){
        wsrc = (const f32x2*)(Whh + (size_t)2*H*H + (size_t)row*H);
        bias = bih[2*H+row] + bhh[2*H+row];
      }
    }
  } else {
    if (wv<2){            // L3 ih (Wih[2], src = staged h2)
      dt=0; srcH2=true; partIdx=0;
      if (row<H) wsrc = (const f32x2*)(Wih + (size_t)2*H*H + (size_t)row*H);
    } else if (wv<4){     // L3 hh
      dt=0; hh=true; dstL=0; srcL=0; partIdx=0;
      if (row<H){
        wsrc = (const f32x2*)(Whh + (size_t)3*H*H + (size_t)row*H);
        bias = bih[3*H+row] + bhh[3*H+row];
      }
    } else if (wv<6){     // L4 ih (Wih[3])
      dt=1; srcL=0; partIdx=1;
      if (row<H) wsrc = (const f32x2*)(Wih + (size_t)3*H*H + (size_t)row*H);
    } else if (wv<8){     // L4 hh
      dt=1; hh=true; dstL=1; srcL=1; partIdx=1;
      if (row<H){
        wsrc = (const f32x2*)(Whh + (size_t)4*H*H + (size_t)row*H);
        bias = bih[4*H+row] + bhh[4*H+row];
      }
    } else if (wv==8){    // out projection
      dt=2; isOut=true; srcL=1;
      if (lane<OUTN){
        wsrc = (const f32x2*)(Wout + (size_t)lane*H);
        bias = bout[lane];
      }
    }                     // wv9: idle (barriers only)
  }

  if (wsrc){              // one load site
    P0 =wsrc[0];  P1 =wsrc[1];  P2 =wsrc[2];  P3 =wsrc[3];  P4 =wsrc[4];
    P5 =wsrc[5];  P6 =wsrc[6];  P7 =wsrc[7];  P8 =wsrc[8];  P9 =wsrc[9];
    P10=wsrc[10]; P11=wsrc[11]; P12=wsrc[12]; P13=wsrc[13]; P14=wsrc[14];
    P15=wsrc[15]; P16=wsrc[16]; P17=wsrc[17]; P18=wsrc[18]; P19=wsrc[19];
    P20=wsrc[20]; P21=wsrc[21]; P22=wsrc[22]; P23=wsrc[23]; P24=wsrc[24];
    P25=wsrc[25]; P26=wsrc[26]; P27=wsrc[27]; P28=wsrc[28]; P29=wsrc[29];
    P30=wsrc[30]; P31=wsrc[31]; P32=wsrc[32]; P33=wsrc[33]; P34=wsrc[34];
    P35=wsrc[35]; P36=wsrc[36]; P37=wsrc[37]; P38=wsrc[38]; P39=wsrc[39];
    P40=wsrc[40]; P41=wsrc[41]; P42=wsrc[42]; P43=wsrc[43]; P44=wsrc[44];
    P45=wsrc[45]; P46=wsrc[46]; P47=wsrc[47]; P48=wsrc[48]; P49=wsrc[49];
  }
  if (usrc){ U0=usrc[0]; U1=usrc[1]; U2=usrc[2]; U3=usrc[3]; U4=usrc[4]; }

  // Opacity barriers: asm-defined values cannot be rematerialized.
  asm volatile("" : "+v"(P0),"+v"(P1),"+v"(P2),"+v"(P3),"+v"(P4),
                    "+v"(P5),"+v"(P6),"+v"(P7),"+v"(P8),"+v"(P9));
  asm volatile("" : "+v"(P10),"+v"(P11),"+v"(P12),"+v"(P13),"+v"(P14),
                    "+v"(P15),"+v"(P16),"+v"(P17),"+v"(P18),"+v"(P19));
  asm volatile("" : "+v"(P20),"+v"(P21),"+v"(P22),"+v"(P23),"+v"(P24),
                    "+v"(P25),"+v"(P26),"+v"(P27),"+v"(P28),"+v"(P29));
  asm volatile("" : "+v"(P30),"+v"(P31),"+v"(P32),"+v"(P33),"+v"(P34),
                    "+v"(P35),"+v"(P36),"+v"(P37),"+v"(P38),"+v"(P39));
  asm volatile("" : "+v"(P40),"+v"(P41),"+v"(P42),"+v"(P43),"+v"(P44),
                    "+v"(P45),"+v"(P46),"+v"(P47),"+v"(P48),"+v"(P49));
  asm volatile("" : "+v"(U0),"+v"(U1),"+v"(U2),"+v"(U3),"+v"(U4));

  // ---- LDS init ------------------------------------------------------------
  if (tid < 3*128){
    int l = tid>>7, r = tid&127;
    bool use = isA ? true : (l<2);
    if (use){
      int gl = isA ? l : (l+3);
      float v = 0.f;
      if (r<H) v = hprev[((size_t)gl*NB+b)*H + r];
      hb[l][1][r] = v;  hb[l][0][r] = 0.f;
    }
  }
  if (isA && wv==0){
    if (lane<NIN){
      size_t x0 = (size_t)b*T*NIN;
      xst[0][lane] = xg[x0+lane];
      xst[1][lane] = xg[x0+NIN+lane];
    } else if (lane<12){
      xst[0][lane]=0.f; xst[1][lane]=0.f;
    }
  }
  if (!isA && wv==8){     // pre-stage h2[0]
    while (__hip_atomic_load(progp, __ATOMIC_ACQUIRE, __HIP_MEMORY_SCOPE_AGENT) < 1)
      __builtin_amdgcn_s_sleep(2);
    if (lane<28){
      size_t base = (size_t)(b*ringSlots)*112;
      ((float4*)h2l[0])[lane] = ((const float4*)(ring+base))[lane];
    }
    if (lane==0)
      __hip_atomic_store(consp, 1, __ATOMIC_RELEASE, __HIP_MEMORY_SCOPE_AGENT);
  }
  __syncthreads();

  // ---- main pipelined loop -------------------------------------------------
  float y0=0,y1=0,y2=0,y3=0,y4=0,y5=0,y6=0,y7=0;
  const size_t yBase  = (size_t)b*T*OUTN;
  const size_t hfBase = (size_t)NB*T*OUTN;
  float xr = 0.f;

  for (int s=0; s<=T+1; ++s){
    const int t = s - dt;
    const bool act = (t>=0) && (t<T);
    float a = 0.f;

    if (isA && wv==0){                       // backpressure + publish
      int t2 = s-2;
      if (t2 >= ringSlots){
        while (__hip_atomic_load(consp, __ATOMIC_ACQUIRE, __HIP_MEMORY_SCOPE_AGENT)
               < t2 - ringSlots + 1)
          __builtin_amdgcn_s_sleep(2);
      }
      if (s>=3 && lane==0)
        __hip_atomic_store(progp, s-2, __ATOMIC_RELEASE, __HIP_MEMORY_SCOPE_AGENT);
    }

    if (act){
      const int slot = hh ? ((t&1)^1) : (t&1);
      const float4* h4p = srcH2 ? (const float4*)h2l[slot]
                                : (const float4*)hb[srcL][slot];
      f32x2 A0, A1={0,0}, A2={0,0}, A3={0,0};
      A0.x = bias; A0.y = 0.f;
#define MV(i,PA,PB,AX,AY) { float4 hv=h4p[i]; \
      f32x2 lo; lo.x=hv.x; lo.y=hv.y; f32x2 hi; hi.x=hv.z; hi.y=hv.w; \
      asm("v_pk_fma_f32 %0, %1, %2, %0" : "+v"(AX) : "v"(PA), "v"(lo)); \
      asm("v_pk_fma_f32 %0, %1, %2, %0" : "+v"(AY) : "v"(PB), "v"(hi)); }
      MV(0,P0,P1,A0,A1)    MV(1,P2,P3,A2,A3)    MV(2,P4,P5,A0,A1)
      MV(3,P6,P7,A2,A3)    MV(4,P8,P9,A0,A1)    MV(5,P10,P11,A2,A3)
      MV(6,P12,P13,A0,A1)  MV(7,P14,P15,A2,A3)  MV(8,P16,P17,A0,A1)
      MV(9,P18,P19,A2,A3)  MV(10,P20,P21,A0,A1) MV(11,P22,P23,A2,A3)
      MV(12,P24,P25,A0,A1) MV(13,P26,P27,A2,A3) MV(14,P28,P29,A0,A1)
      MV(15,P30,P31,A2,A3) MV(16,P32,P33,A0,A1) MV(17,P34,P35,A2,A3)
      MV(18,P36,P37,A0,A1) MV(19,P38,P39,A2,A3) MV(20,P40,P41,A0,A1)
      MV(21,P42,P43,A2,A3) MV(22,P44,P45,A0,A1) MV(23,P46,P47,A2,A3)
      MV(24,P48,P49,A0,A1)
#undef MV
      if (hasX){
        const f32x2* xp2 = (const f32x2*)xst[t&1];
#define MX(i,Un,AX) { f32x2 xv=xp2[i]; \
      asm("v_pk_fma_f32 %0, %1, %2, %0" : "+v"(AX) : "v"(Un), "v"(xv)); }
        MX(0,U0,A2) MX(1,U1,A3) MX(2,U2,A0) MX(3,U3,A1) MX(4,U4,A2)
#undef MX
      }
      a = ((A0.x+A0.y)+(A1.x+A1.y)) + ((A2.x+A2.y)+(A3.x+A3.y));
      if (partIdx>=0 && !hh) part[partIdx][row] = a;
    }

    if (!isA && wv==8 && (s+1)<T){           // poll + stage h2[s+1]
      while (__hip_atomic_load(progp, __ATOMIC_ACQUIRE, __HIP_MEMORY_SCOPE_AGENT) < s+2)
        __builtin_amdgcn_s_sleep(2);
      if (lane<28){
        size_t base = (size_t)(b*ringSlots + ((s+1)&rmask))*112;
        ((float4*)h2l[(s+1)&1])[lane] = ((const float4*)(ring+base))[lane];
      }
      if (lane==0)
        __hip_atomic_store(consp, s+2, __ATOMIC_RELEASE, __HIP_MEMORY_SCOPE_AGENT);
    }
    if (isA && wv==0 && lane<NIN && (s+2)<T)  // x prefetch (2-step lookahead)
      xr = xg[(size_t)b*T*NIN + (size_t)(s+2)*NIN + lane];
    __syncthreads();

    // phase B: finalize / output
    if (act && hh){
      float v = a;
      if (partIdx>=0) v += part[partIdx][row];
      float hval = ftanh(v);
      hb[dstL][t&1][row] = hval;
      if (ringSt && row<H)
        ring[(size_t)(b*ringSlots + (t&rmask))*112 + row] = hval;
      if (t==T-1 && row<H){
        int gl = isA ? dstL : dstL+3;
        outf[hfBase + ((size_t)gl*NB + b)*H + row] = hval;
      }
    }
    if (isOut && act && lane<OUTN){
      const int ph = t&7;                     // named-reg rotation (no alloca)
      y0 = (ph==0)?a:y0;  y1 = (ph==1)?a:y1;
      y2 = (ph==2)?a:y2;  y3 = (ph==3)?a:y3;
      y4 = (ph==4)?a:y4;  y5 = (ph==5)?a:y5;
      y6 = (ph==6)?a:y6;  y7 = (ph==7)?a:y7;
      if (ph==7){
        size_t basei = yBase + (size_t)(t-7)*OUTN + lane;
        outf[basei+0*OUTN]=y0; outf[basei+1*OUTN]=y1;
        outf[basei+2*OUTN]=y2; outf[basei+3*OUTN]=y3;
        outf[basei+4*OUTN]=y4; outf[basei+5*OUTN]=y5;
        outf[basei+6*OUTN]=y6; outf[basei+7*OUTN]=y7;
      }
    }
    if (isA && wv==0 && lane<NIN && (s+2)<T)
      xst[s&1][lane] = xr;                   // slot s&1 == (s+2)&1
    __syncthreads();
  }
  if (isA && wv==0 && lane==0)
    __hip_atomic_store(progp, T, __ATOMIC_RELEASE, __HIP_MEMORY_SCOPE_AGENT);
}

extern "C" void kernel_launch(void* const* d_in, const int* in_sizes, int n_in,
                              void* d_out, int out_size, void* d_ws, size_t ws_size,
                              hipStream_t stream){
  int* flags = (int*)d_ws;                       // 0xAA poison => negative ints
  size_t flagBytes = (size_t)2*NB*32*sizeof(int);
  float* ring = (float*)((char*)d_ws + flagBytes);
  size_t availF = ws_size > flagBytes ? (ws_size - flagBytes)/sizeof(float) : 0;
  int slots = 64;
  while (slots > 2 && (size_t)NB*slots*112 > availF) slots >>= 1;
  rnn5<<<dim3(2*NB), dim3(640), 0, stream>>>(
    (const float*)d_in[0], (const float*)d_in[1], (const float*)d_in[2],
    (const float*)d_in[3], (const float*)d_in[4], (const float*)d_in[5],
    (const float*)d_in[6], (const float*)d_in[7], (const float*)d_in[8],
    (float*)d_out, ring, flags, slots);
}

// Round 9
// 2268.086 us; speedup vs baseline: 2.5755x; 2.5755x over previous
//
#include <hip/hip_runtime.h>

typedef unsigned int u32;
typedef unsigned short u16;
typedef float f32x2 __attribute__((ext_vector_type(2)));

constexpr int NIN = 10, H = 100, OUTN = 10, NL = 5, NB = 64, T = 2048;
constexpr int KB = 16;   // handshake batch (steps per publish/poll)

__device__ __forceinline__ float ftanh(float x){
  float e = __expf(x + x);
  return 1.0f - 2.0f/(e + 1.0f);
}

// Two blocks per batch row (grid 128): block b = layers 0..2, block b+64 =
// layers 3..4 + out. Full fp32 (half-precision state saturates ~5e-2).
// R7/R8 post-mortem: identical dur with changed allocator budget => the
// bottleneck is the PER-STEP agent-scope release/acquire round trip through
// L3 (acquire = whole-XCD L2 invalidate + ~700cy cross-XCD load, on the
// barrier critical chain of BOTH blocks). This round: handshake batched 16x
// (publish/poll once per 16 steps, 16-slot LDS staging of h2), relaxed-spin
// + single acquire, publish-before-wait (deadlock-order safe).
__global__ __launch_bounds__(640)
__attribute__((amdgpu_waves_per_eu(3, 3)))
void rnn5(const float* __restrict__ xg, const float* __restrict__ hprev,
          const float* __restrict__ Wih0, const float* __restrict__ Wih,
          const float* __restrict__ Whh, const float* __restrict__ bih,
          const float* __restrict__ bhh, const float* __restrict__ Wout,
          const float* __restrict__ bout, float* __restrict__ outf,
          float* __restrict__ ring, int* __restrict__ flags, int ringSlots)
{
  __shared__ __align__(16) float hb[3][2][128];   // A: h0,h1,h2 ; B: h3,h4
  __shared__ __align__(16) float part[2][128];    // ih partials
  __shared__ __align__(16) float h2l[KB][112];    // B: staged h2, 16 slots
  __shared__ __align__(16) float xst[2][12];      // A: staged x[t]

  const int tid = threadIdx.x, wv = tid>>6, lane = tid&63;
  const bool isA = (blockIdx.x < NB);
  const int b = isA ? (int)blockIdx.x : (int)blockIdx.x - NB;
  const int rmask = ringSlots - 1;
  int* progp = flags + b*32;            // h2 ready-count (A publishes)
  int* consp = flags + NB*32 + b*32;    // h2 consumed-count (B publishes)
  const int row = ((wv&1)?64:0) + lane;
  const float4* ring4 = (const float4*)ring;

  // ---- role setup ----------------------------------------------------------
  f32x2 P0={0,0},P1=P0,P2=P0,P3=P0,P4=P0,P5=P0,P6=P0,P7=P0,P8=P0,P9=P0,
        P10=P0,P11=P0,P12=P0,P13=P0,P14=P0,P15=P0,P16=P0,P17=P0,P18=P0,P19=P0,
        P20=P0,P21=P0,P22=P0,P23=P0,P24=P0,P25=P0,P26=P0,P27=P0,P28=P0,P29=P0,
        P30=P0,P31=P0,P32=P0,P33=P0,P34=P0,P35=P0,P36=P0,P37=P0,P38=P0,P39=P0,
        P40=P0,P41=P0,P42=P0,P43=P0,P44=P0,P45=P0,P46=P0,P47=P0,P48=P0,P49=P0;
  f32x2 U0={0,0},U1=U0,U2=U0,U3=U0,U4=U0;
  float bias = 0.f;
  int dt = 1<<20, srcL = 0, partIdx = -1, dstL = 0;
  bool srcH2=false, hh=false, hasX=false, ringSt=false, isOut=false;
  const f32x2* wsrc = nullptr;
  const f32x2* usrc = nullptr;

  if (isA){
    if (wv<2){            // L0 hh + x
      dt=0; hh=true; dstL=0; srcL=0; hasX=true;
      if (row<H){
        wsrc = (const f32x2*)(Whh + (size_t)row*H);
        usrc = (const f32x2*)(Wih0 + (size_t)row*NIN);
        bias = bih[row] + bhh[row];
      }
    } else if (wv<4){     // L1 ih (Wih[0])
      dt=1; srcL=0; partIdx=0;
      if (row<H) wsrc = (const f32x2*)(Wih + (size_t)row*H);
    } else if (wv<6){     // L1 hh
      dt=1; hh=true; dstL=1; srcL=1; partIdx=0;
      if (row<H){
        wsrc = (const f32x2*)(Whh + (size_t)1*H*H + (size_t)row*H);
        bias = bih[1*H+row] + bhh[1*H+row];
      }
    } else if (wv<8){     // L2 ih (Wih[1])
      dt=2; srcL=1; partIdx=1;
      if (row<H) wsrc = (const f32x2*)(Wih + (size_t)1*H*H + (size_t)row*H);
    } else {              // L2 hh + ring store
      dt=2; hh=true; dstL=2; srcL=2; partIdx=1; ringSt=true;
      if (row<H){
        wsrc = (const f32x2*)(Whh + (size_t)2*H*H + (size_t)row*H);
        bias = bih[2*H+row] + bhh[2*H+row];
      }
    }
  } else {
    if (wv<2){            // L3 ih (Wih[2], src = staged h2)
      dt=0; srcH2=true; partIdx=0;
      if (row<H) wsrc = (const f32x2*)(Wih + (size_t)2*H*H + (size_t)row*H);
    } else if (wv<4){     // L3 hh
      dt=0; hh=true; dstL=0; srcL=0; partIdx=0;
      if (row<H){
        wsrc = (const f32x2*)(Whh + (size_t)3*H*H + (size_t)row*H);
        bias = bih[3*H+row] + bhh[3*H+row];
      }
    } else if (wv<6){     // L4 ih (Wih[3])
      dt=1; srcL=0; partIdx=1;
      if (row<H) wsrc = (const f32x2*)(Wih + (size_t)3*H*H + (size_t)row*H);
    } else if (wv<8){     // L4 hh
      dt=1; hh=true; dstL=1; srcL=1; partIdx=1;
      if (row<H){
        wsrc = (const f32x2*)(Whh + (size_t)4*H*H + (size_t)row*H);
        bias = bih[4*H+row] + bhh[4*H+row];
      }
    } else if (wv==8){    // out projection
      dt=2; isOut=true; srcL=1;
      if (lane<OUTN){
        wsrc = (const f32x2*)(Wout + (size_t)lane*H);
        bias = bout[lane];
      }
    }                     // wv9: idle (barriers only)
  }

  if (wsrc){              // one load site
    P0 =wsrc[0];  P1 =wsrc[1];  P2 =wsrc[2];  P3 =wsrc[3];  P4 =wsrc[4];
    P5 =wsrc[5];  P6 =wsrc[6];  P7 =wsrc[7];  P8 =wsrc[8];  P9 =wsrc[9];
    P10=wsrc[10]; P11=wsrc[11]; P12=wsrc[12]; P13=wsrc[13]; P14=wsrc[14];
    P15=wsrc[15]; P16=wsrc[16]; P17=wsrc[17]; P18=wsrc[18]; P19=wsrc[19];
    P20=wsrc[20]; P21=wsrc[21]; P22=wsrc[22]; P23=wsrc[23]; P24=wsrc[24];
    P25=wsrc[25]; P26=wsrc[26]; P27=wsrc[27]; P28=wsrc[28]; P29=wsrc[29];
    P30=wsrc[30]; P31=wsrc[31]; P32=wsrc[32]; P33=wsrc[33]; P34=wsrc[34];
    P35=wsrc[35]; P36=wsrc[36]; P37=wsrc[37]; P38=wsrc[38]; P39=wsrc[39];
    P40=wsrc[40]; P41=wsrc[41]; P42=wsrc[42]; P43=wsrc[43]; P44=wsrc[44];
    P45=wsrc[45]; P46=wsrc[46]; P47=wsrc[47]; P48=wsrc[48]; P49=wsrc[49];
  }
  if (usrc){ U0=usrc[0]; U1=usrc[1]; U2=usrc[2]; U3=usrc[3]; U4=usrc[4]; }

  // Opacity barriers: asm-defined values cannot be rematerialized.
  asm volatile("" : "+v"(P0),"+v"(P1),"+v"(P2),"+v"(P3),"+v"(P4),
                    "+v"(P5),"+v"(P6),"+v"(P7),"+v"(P8),"+v"(P9));
  asm volatile("" : "+v"(P10),"+v"(P11),"+v"(P12),"+v"(P13),"+v"(P14),
                    "+v"(P15),"+v"(P16),"+v"(P17),"+v"(P18),"+v"(P19));
  asm volatile("" : "+v"(P20),"+v"(P21),"+v"(P22),"+v"(P23),"+v"(P24),
                    "+v"(P25),"+v"(P26),"+v"(P27),"+v"(P28),"+v"(P29));
  asm volatile("" : "+v"(P30),"+v"(P31),"+v"(P32),"+v"(P33),"+v"(P34),
                    "+v"(P35),"+v"(P36),"+v"(P37),"+v"(P38),"+v"(P39));
  asm volatile("" : "+v"(P40),"+v"(P41),"+v"(P42),"+v"(P43),"+v"(P44),
                    "+v"(P45),"+v"(P46),"+v"(P47),"+v"(P48),"+v"(P49));
  asm volatile("" : "+v"(U0),"+v"(U1),"+v"(U2),"+v"(U3),"+v"(U4));

  // ---- LDS init ------------------------------------------------------------
  if (tid < 3*128){
    int l = tid>>7, r = tid&127;
    bool use = isA ? true : (l<2);
    if (use){
      int gl = isA ? l : (l+3);
      float v = 0.f;
      if (r<H) v = hprev[((size_t)gl*NB+b)*H + r];
      hb[l][1][r] = v;  hb[l][0][r] = 0.f;
    }
  }
  if (isA && wv==0){
    if (lane<NIN){
      size_t x0 = (size_t)b*T*NIN;
      xst[0][lane] = xg[x0+lane];
      xst[1][lane] = xg[x0+NIN+lane];
    } else if (lane<12){
      xst[0][lane]=0.f; xst[1][lane]=0.f;
    }
  }
  if (!isA && wv==8){     // pre-stage batch 0: slots 0..15
    while (__hip_atomic_load(progp, __ATOMIC_RELAXED, __HIP_MEMORY_SCOPE_AGENT) < KB)
      __builtin_amdgcn_s_sleep(8);
    (void)__hip_atomic_load(progp, __ATOMIC_ACQUIRE, __HIP_MEMORY_SCOPE_AGENT);
    for (int i=lane; i<KB*28; i+=64){
      int sl = i/28, off = i - sl*28;
      ((float4*)h2l)[i] = ring4[((size_t)b*ringSlots + (sl&rmask))*28 + off];
    }
    if (lane==0)
      __hip_atomic_store(consp, KB, __ATOMIC_RELEASE, __HIP_MEMORY_SCOPE_AGENT);
  }
  __syncthreads();

  // ---- main pipelined loop -------------------------------------------------
  float y0=0,y1=0,y2=0,y3=0,y4=0,y5=0,y6=0,y7=0;
  const size_t yBase  = (size_t)b*T*OUTN;
  const size_t hfBase = (size_t)NB*T*OUTN;
  float xr = 0.f;

  for (int s=0; s<=T+1; ++s){
    const int t = s - dt;
    const bool act = (t>=0) && (t<T);
    float a = 0.f;

    if (isA && wv==0 && ((s-2)&(KB-1))==0 && s>=KB+2){
      // batched publish (FIRST: deadlock-order) + backpressure (1/16 steps)
      if (lane==0)
        __hip_atomic_store(progp, s-2, __ATOMIC_RELEASE, __HIP_MEMORY_SCOPE_AGENT);
      int need = (s-2) - (ringSlots - KB);   // don't overwrite unconsumed slots
      if (need > 0){
        while (__hip_atomic_load(consp, __ATOMIC_RELAXED, __HIP_MEMORY_SCOPE_AGENT) < need)
          __builtin_amdgcn_s_sleep(8);
        (void)__hip_atomic_load(consp, __ATOMIC_ACQUIRE, __HIP_MEMORY_SCOPE_AGENT);
      }
    }

    if (act){
      const int slot = hh ? ((t&1)^1) : (t&1);
      const float4* h4p = srcH2 ? (const float4*)h2l[t&(KB-1)]
                                : (const float4*)hb[srcL][slot];
      f32x2 A0, A1={0,0}, A2={0,0}, A3={0,0};
      A0.x = bias; A0.y = 0.f;
#define MV(i,PA,PB,AX,AY) { float4 hv=h4p[i]; \
      f32x2 lo; lo.x=hv.x; lo.y=hv.y; f32x2 hi; hi.x=hv.z; hi.y=hv.w; \
      asm("v_pk_fma_f32 %0, %1, %2, %0" : "+v"(AX) : "v"(PA), "v"(lo)); \
      asm("v_pk_fma_f32 %0, %1, %2, %0" : "+v"(AY) : "v"(PB), "v"(hi)); }
      MV(0,P0,P1,A0,A1)    MV(1,P2,P3,A2,A3)    MV(2,P4,P5,A0,A1)
      MV(3,P6,P7,A2,A3)    MV(4,P8,P9,A0,A1)    MV(5,P10,P11,A2,A3)
      MV(6,P12,P13,A0,A1)  MV(7,P14,P15,A2,A3)  MV(8,P16,P17,A0,A1)
      MV(9,P18,P19,A2,A3)  MV(10,P20,P21,A0,A1) MV(11,P22,P23,A2,A3)
      MV(12,P24,P25,A0,A1) MV(13,P26,P27,A2,A3) MV(14,P28,P29,A0,A1)
      MV(15,P30,P31,A2,A3) MV(16,P32,P33,A0,A1) MV(17,P34,P35,A2,A3)
      MV(18,P36,P37,A0,A1) MV(19,P38,P39,A2,A3) MV(20,P40,P41,A0,A1)
      MV(21,P42,P43,A2,A3) MV(22,P44,P45,A0,A1) MV(23,P46,P47,A2,A3)
      MV(24,P48,P49,A0,A1)
#undef MV
      if (hasX){
        const f32x2* xp2 = (const f32x2*)xst[t&1];
#define MX(i,Un,AX) { f32x2 xv=xp2[i]; \
      asm("v_pk_fma_f32 %0, %1, %2, %0" : "+v"(AX) : "v"(Un), "v"(xv)); }
        MX(0,U0,A2) MX(1,U1,A3) MX(2,U2,A0) MX(3,U3,A1) MX(4,U4,A2)
#undef MX
      }
      a = ((A0.x+A0.y)+(A1.x+A1.y)) + ((A2.x+A2.y)+(A3.x+A3.y));
      if (partIdx>=0 && !hh) part[partIdx][row] = a;
    }

    if (!isA && wv==8 && ((s+1)&(KB-1))==0 && (s+1)<T){
      // batched poll + stage next 16 h2 slots (1/16 steps)
      const int m = s+1;
      int target = m + KB; if (target > T) target = T;
      while (__hip_atomic_load(progp, __ATOMIC_RELAXED, __HIP_MEMORY_SCOPE_AGENT) < target)
        __builtin_amdgcn_s_sleep(8);
      (void)__hip_atomic_load(progp, __ATOMIC_ACQUIRE, __HIP_MEMORY_SCOPE_AGENT);
      for (int i=lane; i<KB*28; i+=64){
        int sl = i/28, off = i - sl*28;
        ((float4*)h2l)[i] = ring4[((size_t)b*ringSlots + ((m+sl)&rmask))*28 + off];
      }
      if (lane==0)
        __hip_atomic_store(consp, m+KB, __ATOMIC_RELEASE, __HIP_MEMORY_SCOPE_AGENT);
    }
    if (isA && wv==0 && lane<NIN && (s+2)<T)  // x prefetch (2-step lookahead)
      xr = xg[(size_t)b*T*NIN + (size_t)(s+2)*NIN + lane];
    __syncthreads();

    // phase B: finalize / output
    if (act && hh){
      float v = a;
      if (partIdx>=0) v += part[partIdx][row];
      float hval = ftanh(v);
      hb[dstL][t&1][row] = hval;
      if (ringSt && row<H)
        ring[(size_t)(b*ringSlots + (t&rmask))*112 + row] = hval;
      if (t==T-1 && row<H){
        int gl = isA ? dstL : dstL+3;
        outf[hfBase + ((size_t)gl*NB + b)*H + row] = hval;
      }
    }
    if (isOut && act && lane<OUTN){
      const int ph = t&7;                     // named-reg rotation (no alloca)
      y0 = (ph==0)?a:y0;  y1 = (ph==1)?a:y1;
      y2 = (ph==2)?a:y2;  y3 = (ph==3)?a:y3;
      y4 = (ph==4)?a:y4;  y5 = (ph==5)?a:y5;
      y6 = (ph==6)?a:y6;  y7 = (ph==7)?a:y7;
      if (ph==7){
        size_t basei = yBase + (size_t)(t-7)*OUTN + lane;
        outf[basei+0*OUTN]=y0; outf[basei+1*OUTN]=y1;
        outf[basei+2*OUTN]=y2; outf[basei+3*OUTN]=y3;
        outf[basei+4*OUTN]=y4; outf[basei+5*OUTN]=y5;
        outf[basei+6*OUTN]=y6; outf[basei+7*OUTN]=y7;
      }
    }
    if (isA && wv==0 && lane<NIN && (s+2)<T)
      xst[s&1][lane] = xr;                   // slot s&1 == (s+2)&1
    __syncthreads();
  }
  if (isA && wv==0 && lane==0)
    __hip_atomic_store(progp, T, __ATOMIC_RELEASE, __HIP_MEMORY_SCOPE_AGENT);
}

extern "C" void kernel_launch(void* const* d_in, const int* in_sizes, int n_in,
                              void* d_out, int out_size, void* d_ws, size_t ws_size,
                              hipStream_t stream){
  int* flags = (int*)d_ws;                       // 0xAA poison => negative ints
  size_t flagBytes = (size_t)2*NB*32*sizeof(int);
  float* ring = (float*)((char*)d_ws + flagBytes);
  size_t availF = ws_size > flagBytes ? (ws_size - flagBytes)/sizeof(float) : 0;
  int slots = 64;
  while (slots > 2 && (size_t)NB*slots*112 > availF) slots >>= 1;
  rnn5<<<dim3(2*NB), dim3(640), 0, stream>>>(
    (const float*)d_in[0], (const float*)d_in[1], (const float*)d_in[2],
    (const float*)d_in[3], (const float*)d_in[4], (const float*)d_in[5],
    (const float*)d_in[6], (const float*)d_in[7], (const float*)d_in[8],
    (float*)d_out, ring, flags, slots);
}

// Round 10
// 2133.988 us; speedup vs baseline: 2.7373x; 1.0628x over previous
//
#include <hip/hip_runtime.h>

typedef float f32x2 __attribute__((ext_vector_type(2)));

constexpr int H=100, NIN=10, OUTN=10, NB=64, T=2048, KB=16;

__device__ __forceinline__ float ftanh(float x){
  float e=__expf(x+x); return 1.0f - 2.0f/(e+1.0f);
}

// 4-deep block pipeline, 4 blocks per batch row (grid 256 = 1 block/CU).
//   blk0: L0hh(+x) -> ring0 = L1ih partial
//   blk1: L1hh(+ring0) + L2ih -> ring1
//   blk2: L2hh(+ring1) + L3ih -> ring2
//   blk3: L3hh(+ring2) + L4ih + L4hh + out
// Every matvec role = 4 waves, one k-quarter each ({24,28,24,24} of K=100):
// per-lane weights 2 rows x <=28 k = <=56 VGPRs (fits budget, no spills) and
// each role reads h from LDS exactly once (4 disjoint slices) -- r9 re-read
// the full h per wave (~250 b128/step/CU = the 2650cy/step LDS-port wall).
// Quarter partials combine via LDS in phase2; cross-block rings carry the
// summed ih partial, batched-16 handshake (r9-proven), DOUBLE-buffered
// staging (fixes r9's overwrite-while-read race). Full fp32 throughout.
__global__ __launch_bounds__(896)
__attribute__((amdgpu_waves_per_eu(4,4)))
void rnn5(const float* __restrict__ xg, const float* __restrict__ hprev,
          const float* __restrict__ Wih0, const float* __restrict__ Wih,
          const float* __restrict__ Whh, const float* __restrict__ bih,
          const float* __restrict__ bhh, const float* __restrict__ Wout,
          const float* __restrict__ bout, float* __restrict__ outf,
          float* __restrict__ ring, int* __restrict__ flags, int slots)
{
  __shared__ __align__(16) float hbA[2][128];      // this block's lower hh state
  __shared__ __align__(16) float hbB[2][128];      // blk3: h4
  __shared__ __align__(16) float partHH[2][3][128];// hh k-quarters 1..3
  __shared__ __align__(16) float partIH[2][4][128];// ih k-quarters (parity by t)
  __shared__ __align__(16) float sIn[2][KB][112];  // staged incoming partials
  __shared__ __align__(16) float xst[2][12];       // blk0: staged x[t]

  const int tid=threadIdx.x, wv=tid>>6, lane=tid&63;
  const int bt=blockIdx.x>>6, b=blockIdx.x&63;
  const int sm1=slots-1;

  // ---- roles ---------------------------------------------------------------
  bool mvOn=false,isHH=false,finalz=false,comb=false,wPIH=false,wPHH=false,
       useB=false,wrB=false,isOut=false,isStg=false,hasX=false,xPre=false,
       inSIn=false,inPIH=false;
  int dtv=1<<20, kqi=0, roleIdx=0, layerHH=0;
  const float* wmat=Whh;

  if (bt==0){
    if (wv<4){ mvOn=true;isHH=true;dtv=0;kqi=wv;finalz=(wv==0);wPHH=(wv>0);
               layerHH=0;wmat=Whh;hasX=true; }
    else if (wv<8){ mvOn=true;dtv=1;kqi=wv-4;comb=(wv==4);wPIH=(wv>4);
               wmat=Wih; xPre=(wv==7); }
  } else if (bt==3){
    if (wv<4){ mvOn=true;isHH=true;dtv=0;kqi=wv;finalz=(wv==0);wPHH=(wv>0);
               layerHH=3;wmat=Whh+(size_t)3*H*H;inSIn=(wv==0); }
    else if (wv<8){ mvOn=true;dtv=1;kqi=wv-4;wPIH=true;
               wmat=Wih+(size_t)3*H*H; }
    else if (wv<12){ mvOn=true;isHH=true;dtv=2;kqi=wv-8;finalz=(wv==8);
               wPHH=(wv>8);roleIdx=1;layerHH=4;wmat=Whh+(size_t)4*H*H;
               useB=true;wrB=true;inPIH=(wv==8); }
    else if (wv==12){ mvOn=true;isOut=true;dtv=3;useB=true;wmat=Wout; }
    else { isStg=true; }
  } else {            // bt 1,2
    if (wv<4){ mvOn=true;isHH=true;dtv=0;kqi=wv;finalz=(wv==0);wPHH=(wv>0);
               layerHH=bt;wmat=Whh+(size_t)bt*H*H;inSIn=(wv==0); }
    else if (wv<8){ mvOn=true;dtv=1;kqi=wv-4;comb=(wv==4);wPIH=(wv>4);
               wmat=Wih+(size_t)bt*H*H; }
    else if (wv==8){ isStg=true; }
  }

  const int koffT[4]={0,24,52,76}, klenT[4]={24,28,24,24};
  const int q = isOut ? (lane<40 ? lane/10 : 3) : kqi;
  const int koffv=koffT[q], klenv=klenT[q];
  const int r0 = isOut ? (lane<40 ? (lane - (lane/10)*10) : H) : 2*lane;
  const int r1 = isOut ? H : 2*lane+1;
  const int r0c=(r0<H)?r0:0, r1c=(r1<H)?r1:0;
  const float mA=(mvOn && r0<H)?1.f:0.f;
  const float mB=(mvOn && r1<H)?1.f:0.f;

  // ---- weights: 2 rows x up to 14 f32x2 (adjacent-k pairs), masked loads ---
  f32x2 z2; z2.x=0.f; z2.y=0.f;
  f32x2 WA0=z2,WA1=z2,WA2=z2,WA3=z2,WA4=z2,WA5=z2,WA6=z2,WA7=z2,WA8=z2,
        WA9=z2,WA10=z2,WA11=z2,WA12=z2,WA13=z2;
  f32x2 WB0=z2,WB1=z2,WB2=z2,WB3=z2,WB4=z2,WB5=z2,WB6=z2,WB7=z2,WB8=z2,
        WB9=z2,WB10=z2,WB11=z2,WB12=z2,WB13=z2;
#define LW(J,WAJ,WBJ) { const int off=koffv+2*(J); const int offc=(off<=98)?off:96; \
  const float mj=((2*(J))<klenv)?1.f:0.f; const float ma=mA*mj, mb=mB*mj; \
  f32x2 la=*(const f32x2*)(wmat+(size_t)r0c*H+offc); \
  f32x2 lb=*(const f32x2*)(wmat+(size_t)r1c*H+offc); \
  WAJ.x=la.x*ma; WAJ.y=la.y*ma; WBJ.x=lb.x*mb; WBJ.y=lb.y*mb; }
  LW(0,WA0,WB0)  LW(1,WA1,WB1)  LW(2,WA2,WB2)  LW(3,WA3,WB3)
  LW(4,WA4,WB4)  LW(5,WA5,WB5)  LW(6,WA6,WB6)  LW(7,WA7,WB7)
  LW(8,WA8,WB8)  LW(9,WA9,WB9)  LW(10,WA10,WB10) LW(11,WA11,WB11)
  LW(12,WA12,WB12) LW(13,WA13,WB13)
#undef LW

  f32x2 XA0=z2,XA1=z2,XB0=z2,XB1=z2;
  int xo=0;
  if (hasX){
    const int xoT[4]={0,4,8,8}, xlT[4]={4,4,2,0};
    xo=xoT[kqi]; const int xl=xlT[kqi];
    { const int c=xo;   const int cc=(c<=8)?c:8; const float mj=(0<xl)?1.f:0.f;
      f32x2 la=*(const f32x2*)(Wih0+(size_t)r0c*NIN+cc);
      f32x2 lb=*(const f32x2*)(Wih0+(size_t)r1c*NIN+cc);
      XA0.x=la.x*(mA*mj); XA0.y=la.y*(mA*mj);
      XB0.x=lb.x*(mB*mj); XB0.y=lb.y*(mB*mj); }
    { const int c=xo+2; const int cc=(c<=8)?c:8; const float mj=(2<xl)?1.f:0.f;
      f32x2 la=*(const f32x2*)(Wih0+(size_t)r0c*NIN+cc);
      f32x2 lb=*(const f32x2*)(Wih0+(size_t)r1c*NIN+cc);
      XA1.x=la.x*(mA*mj); XA1.y=la.y*(mA*mj);
      XB1.x=lb.x*(mB*mj); XB1.y=lb.y*(mB*mj); }
  }

  f32x2 biasP=z2;
  if (finalz){
    if (r0<H) biasP.x = bih[layerHH*H+r0]+bhh[layerHH*H+r0];
    if (r1<H) biasP.y = bih[layerHH*H+r1]+bhh[layerHH*H+r1];
  }

  // opacity: asm-defined values cannot be rematerialized
  asm volatile("" : "+v"(WA0),"+v"(WA1),"+v"(WA2),"+v"(WA3),"+v"(WA4),
                    "+v"(WA5),"+v"(WA6),"+v"(WA7));
  asm volatile("" : "+v"(WA8),"+v"(WA9),"+v"(WA10),"+v"(WA11),"+v"(WA12),
                    "+v"(WA13),"+v"(XA0),"+v"(XA1));
  asm volatile("" : "+v"(WB0),"+v"(WB1),"+v"(WB2),"+v"(WB3),"+v"(WB4),
                    "+v"(WB5),"+v"(WB6),"+v"(WB7));
  asm volatile("" : "+v"(WB8),"+v"(WB9),"+v"(WB10),"+v"(WB11),"+v"(WB12),
                    "+v"(WB13),"+v"(XB0),"+v"(XB1));

  // ---- flags / ring bases --------------------------------------------------
  int* progp=nullptr; int* consp=nullptr; int* progc=nullptr; int* consc=nullptr;
  if (bt<3){ progp=flags+(bt*NB+b)*32;     consp=flags+((3+bt)*NB+b)*32; }
  if (bt>0){ progc=flags+((bt-1)*NB+b)*32; consc=flags+((3+bt-1)*NB+b)*32; }
  const size_t rbW=(size_t)(bt*NB+b)*slots*100;                 // producer, floats
  const size_t rbR=(size_t)(((bt>0?bt:1)-1)*NB+b)*slots*25;     // consumer, float4s

  // ---- LDS init ------------------------------------------------------------
  if (tid<128){ int r=tid; hbA[0][r]=0.f; float v=0.f;
    if (r<H) v=hprev[((size_t)bt*NB+b)*H+r];   // bt==layer of hbA owner
    hbA[1][r]=v; }
  else if (tid<256){ int r=tid-128; hbB[0][r]=0.f; float v=0.f;
    if (bt==3 && r<H) v=hprev[((size_t)4*NB+b)*H+r];
    hbB[1][r]=v; }
  if (bt==0 && wv==7 && lane<12){
    float a0=0.f,a1=0.f;
    if (lane<10){ a0=xg[(size_t)b*T*NIN+lane]; a1=xg[(size_t)b*T*NIN+NIN+lane]; }
    xst[0][lane]=a0; xst[1][lane]=a1;
  }
  if (isStg){   // pre-stage batch 0 (slots 0..15) into sIn[0]
    while (__hip_atomic_load(progc,__ATOMIC_RELAXED,__HIP_MEMORY_SCOPE_AGENT)<KB)
      __builtin_amdgcn_s_sleep(8);
    (void)__hip_atomic_load(progc,__ATOMIC_ACQUIRE,__HIP_MEMORY_SCOPE_AGENT);
    const float4* r4=(const float4*)ring;
    float4* d4=(float4*)sIn[0];
    for (int i=lane;i<KB*25;i+=64){ int sl=i/25, off=i-sl*25;
      d4[sl*28+off]=r4[rbR+(size_t)(sl&sm1)*25+off]; }
    if (lane==0)
      __hip_atomic_store(consc,KB,__ATOMIC_RELEASE,__HIP_MEMORY_SCOPE_AGENT);
  }
  __syncthreads();

  // ---- main loop -----------------------------------------------------------
  float y0=0,y1=0,y2=0,y3=0,y4=0,y5=0,y6=0,y7=0, xr=0.f;
  const size_t yB=(size_t)b*T*OUTN, hfB=(size_t)NB*T*OUTN;

  for (int s=0; s<=T+2; ++s){
    const int t=s-dtv;
    const bool act = ((unsigned)t < (unsigned)T);
    float aA=0.f, aB=0.f;

    if (comb && act && (t&(KB-1))==0){       // producer backpressure (1/16)
      const int need = t + KB - slots;
      if (need>0){
        while (__hip_atomic_load(consp,__ATOMIC_RELAXED,__HIP_MEMORY_SCOPE_AGENT)<need)
          __builtin_amdgcn_s_sleep(8);
        (void)__hip_atomic_load(consp,__ATOMIC_ACQUIRE,__HIP_MEMORY_SCOPE_AGENT);
      }
    }

    if (act && mvOn){
      const int sl=(t&1)^(isHH?1:0);
      const float4* h4=(const float4*)((useB?hbB[sl]:hbA[sl])+koffv);
      f32x2 accA=z2, accB=z2;
#define MVQ(J,wa0,wa1,wb0,wb1) { float4 hv=h4[J]; \
      f32x2 p0; p0.x=hv.x; p0.y=hv.y; f32x2 p1; p1.x=hv.z; p1.y=hv.w; \
      asm("v_pk_fma_f32 %0, %1, %2, %0":"+v"(accA):"v"(wa0),"v"(p0)); \
      asm("v_pk_fma_f32 %0, %1, %2, %0":"+v"(accB):"v"(wb0),"v"(p0)); \
      asm("v_pk_fma_f32 %0, %1, %2, %0":"+v"(accA):"v"(wa1),"v"(p1)); \
      asm("v_pk_fma_f32 %0, %1, %2, %0":"+v"(accB):"v"(wb1),"v"(p1)); }
      MVQ(0,WA0,WA1,WB0,WB1)   MVQ(1,WA2,WA3,WB2,WB3)
      MVQ(2,WA4,WA5,WB4,WB5)   MVQ(3,WA6,WA7,WB6,WB7)
      MVQ(4,WA8,WA9,WB8,WB9)   MVQ(5,WA10,WA11,WB10,WB11)
      MVQ(6,WA12,WA13,WB12,WB13)
#undef MVQ
      if (hasX){
        float4 xv=*(const float4*)(xst[t&1]+xo);
        f32x2 p0; p0.x=xv.x; p0.y=xv.y; f32x2 p1; p1.x=xv.z; p1.y=xv.w;
        asm("v_pk_fma_f32 %0, %1, %2, %0":"+v"(accA):"v"(XA0),"v"(p0));
        asm("v_pk_fma_f32 %0, %1, %2, %0":"+v"(accB):"v"(XB0),"v"(p0));
        asm("v_pk_fma_f32 %0, %1, %2, %0":"+v"(accA):"v"(XA1),"v"(p1));
        asm("v_pk_fma_f32 %0, %1, %2, %0":"+v"(accB):"v"(XB1),"v"(p1));
      }
      aA=accA.x+accA.y; aB=accB.x+accB.y;
      if (wPHH){ f32x2 st; st.x=aA; st.y=aB;
        *(f32x2*)&partHH[roleIdx][kqi-1][2*lane]=st; }
      if (wPIH){ f32x2 st; st.x=aA; st.y=aB;
        *(f32x2*)&partIH[t&1][kqi][2*lane]=st; }
    }

    if (isStg && ((s+1)&(KB-1))==0 && (s+1)<T){   // stage next batch (1/16)
      const int m=s+1; int target=m+KB; if (target>T) target=T;
      while (__hip_atomic_load(progc,__ATOMIC_RELAXED,__HIP_MEMORY_SCOPE_AGENT)<target)
        __builtin_amdgcn_s_sleep(8);
      (void)__hip_atomic_load(progc,__ATOMIC_ACQUIRE,__HIP_MEMORY_SCOPE_AGENT);
      const float4* r4=(const float4*)ring;
      float4* d4=(float4*)sIn[(m>>4)&1];
      for (int i=lane;i<KB*25;i+=64){ int sl=i/25, off=i-sl*25;
        d4[sl*28+off]=r4[rbR+(size_t)((m+sl)&sm1)*25+off]; }
      if (lane==0)
        __hip_atomic_store(consc,m+KB,__ATOMIC_RELEASE,__HIP_MEMORY_SCOPE_AGENT);
    }
    if (xPre && lane<10 && (s+2)<T)
      xr = xg[(size_t)b*T*NIN + (size_t)(s+2)*NIN + lane];
    __syncthreads();

    // ---- phase 2 -----------------------------------------------------------
    if (act && finalz){
      f32x2 v; v.x=aA+biasP.x; v.y=aB+biasP.y;
      { f32x2 p=*(const f32x2*)&partHH[roleIdx][0][2*lane]; v.x+=p.x; v.y+=p.y; }
      { f32x2 p=*(const f32x2*)&partHH[roleIdx][1][2*lane]; v.x+=p.x; v.y+=p.y; }
      { f32x2 p=*(const f32x2*)&partHH[roleIdx][2][2*lane]; v.x+=p.x; v.y+=p.y; }
      if (inSIn){ f32x2 p=*(const f32x2*)&sIn[(t>>4)&1][t&(KB-1)][2*lane];
        v.x+=p.x; v.y+=p.y; }
      if (inPIH){
        { f32x2 p=*(const f32x2*)&partIH[t&1][0][2*lane]; v.x+=p.x; v.y+=p.y; }
        { f32x2 p=*(const f32x2*)&partIH[t&1][1][2*lane]; v.x+=p.x; v.y+=p.y; }
        { f32x2 p=*(const f32x2*)&partIH[t&1][2][2*lane]; v.x+=p.x; v.y+=p.y; }
        { f32x2 p=*(const f32x2*)&partIH[t&1][3][2*lane]; v.x+=p.x; v.y+=p.y; }
      }
      const float h0v=ftanh(v.x), h1v=ftanh(v.y);
      if (r0<H){
        f32x2 st; st.x=h0v; st.y=h1v;
        *(f32x2*)&((wrB?hbB:hbA)[t&1][2*lane])=st;
        if (t==T-1)
          *(f32x2*)&outf[hfB+((size_t)layerHH*NB+b)*H+r0]=st;
      }
    }
    if (act && comb){
      f32x2 v; v.x=aA; v.y=aB;
      { f32x2 p=*(const f32x2*)&partIH[t&1][1][2*lane]; v.x+=p.x; v.y+=p.y; }
      { f32x2 p=*(const f32x2*)&partIH[t&1][2][2*lane]; v.x+=p.x; v.y+=p.y; }
      { f32x2 p=*(const f32x2*)&partIH[t&1][3][2*lane]; v.x+=p.x; v.y+=p.y; }
      if (r0<H)
        *(f32x2*)&ring[rbW+(size_t)(t&sm1)*100+r0]=v;
      if ((t&(KB-1))==(KB-1) && lane==0)
        __hip_atomic_store(progp,t+1,__ATOMIC_RELEASE,__HIP_MEMORY_SCOPE_AGENT);
    }
    if (act && isOut){
      float a2=aA+__shfl_down(aA,20,64);
      float yv=a2+__shfl_down(a2,10,64);
      if (lane<OUTN){
        yv += bout[lane];
        const int ph=t&7;
        y0=(ph==0)?yv:y0; y1=(ph==1)?yv:y1; y2=(ph==2)?yv:y2; y3=(ph==3)?yv:y3;
        y4=(ph==4)?yv:y4; y5=(ph==5)?yv:y5; y6=(ph==6)?yv:y6; y7=(ph==7)?yv:y7;
        if (ph==7){
          const size_t bi=yB+(size_t)(t-7)*OUTN+lane;
          outf[bi+0*OUTN]=y0; outf[bi+1*OUTN]=y1; outf[bi+2*OUTN]=y2;
          outf[bi+3*OUTN]=y3; outf[bi+4*OUTN]=y4; outf[bi+5*OUTN]=y5;
          outf[bi+6*OUTN]=y6; outf[bi+7*OUTN]=y7;
        }
      }
    }
    if (xPre && lane<10 && (s+2)<T) xst[s&1][lane]=xr;
    __syncthreads();
  }
  if (comb && lane==0)
    __hip_atomic_store(progp,T,__ATOMIC_RELEASE,__HIP_MEMORY_SCOPE_AGENT);
}

extern "C" void kernel_launch(void* const* d_in, const int* in_sizes, int n_in,
                              void* d_out, int out_size, void* d_ws, size_t ws_size,
                              hipStream_t stream){
  int* flags=(int*)d_ws;                     // 6*64*32 ints; 0xAA poison < 0
  size_t flagBytes=(size_t)6*NB*32*sizeof(int);
  float* ring=(float*)((char*)d_ws+flagBytes);
  size_t availF = ws_size>flagBytes ? (ws_size-flagBytes)/sizeof(float) : 0;
  int slots=64;
  while (slots>32 && (size_t)3*NB*slots*100 > availF) slots>>=1;
  rnn5<<<dim3(256), dim3(896), 0, stream>>>(
    (const float*)d_in[0], (const float*)d_in[1], (const float*)d_in[2],
    (const float*)d_in[3], (const float*)d_in[4], (const float*)d_in[5],
    (const float*)d_in[6], (const float*)d_in[7], (const float*)d_in[8],
    (float*)d_out, ring, flags, slots);
}

// Round 11
// 2080.701 us; speedup vs baseline: 2.8074x; 1.0256x over previous
//
#include <hip/hip_runtime.h>

typedef float f32x2 __attribute__((ext_vector_type(2)));

constexpr int H=100, NIN=10, OUTN=10, NB=64, T=2048, KB=16;

__device__ __forceinline__ float ftanh(float x){
  float e=__expf(x+x); return 1.0f - 2.0f/(e+1.0f);
}

// 4-deep block pipeline, 4 blocks per batch row (grid 256 = 1 block/CU).
//   blk0: L0hh(+x) + L1ih -> ring0 ; blk1: L1hh(+ring0)+L2ih -> ring1
//   blk2: L2hh(+ring1)+L3ih -> ring2 ; blk3: L3hh(+ring2)+L4ih+L4hh+out
// r10 lesson: __syncthreads drains vmcnt(0) -> every in-loop global op costs
// full latency at the next barrier. This round evicts global traffic from the
// steady-state loop: x via lookahead LDS stager (blk0 wv8), ring writes
// batched 8x in named regs (flush 1/8 steps), consumer staging with 16-step
// lookahead (latency hidden), bout hoisted, s_sleep(1). Roles/weights
// byte-identical to r10 (passed, absmax 1.95e-3). Full fp32 throughout.
__global__ __launch_bounds__(896)
__attribute__((amdgpu_waves_per_eu(4,4)))
void rnn5(const float* __restrict__ xg, const float* __restrict__ hprev,
          const float* __restrict__ Wih0, const float* __restrict__ Wih,
          const float* __restrict__ Whh, const float* __restrict__ bih,
          const float* __restrict__ bhh, const float* __restrict__ Wout,
          const float* __restrict__ bout, float* __restrict__ outf,
          float* __restrict__ ring, int* __restrict__ flags, int slots)
{
  __shared__ __align__(16) float hbA[2][128];
  __shared__ __align__(16) float hbB[2][128];
  __shared__ __align__(16) float partHH[2][3][128];
  __shared__ __align__(16) float partIH[2][4][128];
  __shared__ __align__(16) float sIn[4][KB][128];   // staged ring, 4 bufs
  __shared__ __align__(16) float xs[4][KB][12];     // staged x, 4 bufs

  const int tid=threadIdx.x, wv=tid>>6, lane=tid&63;
  const int bt=blockIdx.x>>6, b=blockIdx.x&63;
  const int sm1=slots-1;

  // ---- roles ---------------------------------------------------------------
  bool mvOn=false,isHH=false,finalz=false,comb=false,wPIH=false,wPHH=false,
       useB=false,wrB=false,isOut=false,isStg=false,hasX=false,xStg=false,
       inSIn=false,inPIH=false;
  int dtv=1<<20, kqi=0, roleIdx=0, layerHH=0;
  const float* wmat=Whh;

  if (bt==0){
    if (wv<4){ mvOn=true;isHH=true;dtv=0;kqi=wv;finalz=(wv==0);wPHH=(wv>0);
               layerHH=0;wmat=Whh;hasX=true; }
    else if (wv<8){ mvOn=true;dtv=1;kqi=wv-4;comb=(wv==4);wPIH=(wv>4);
               wmat=Wih; }
    else if (wv==8){ xStg=true; }
  } else if (bt==3){
    if (wv<4){ mvOn=true;isHH=true;dtv=0;kqi=wv;finalz=(wv==0);wPHH=(wv>0);
               layerHH=3;wmat=Whh+(size_t)3*H*H;inSIn=(wv==0); }
    else if (wv<8){ mvOn=true;dtv=1;kqi=wv-4;wPIH=true;
               wmat=Wih+(size_t)3*H*H; }
    else if (wv<12){ mvOn=true;isHH=true;dtv=2;kqi=wv-8;finalz=(wv==8);
               wPHH=(wv>8);roleIdx=1;layerHH=4;wmat=Whh+(size_t)4*H*H;
               useB=true;wrB=true;inPIH=(wv==8); }
    else if (wv==12){ mvOn=true;isOut=true;dtv=3;useB=true;wmat=Wout; }
    else { isStg=true; }
  } else {            // bt 1,2
    if (wv<4){ mvOn=true;isHH=true;dtv=0;kqi=wv;finalz=(wv==0);wPHH=(wv>0);
               layerHH=bt;wmat=Whh+(size_t)bt*H*H;inSIn=(wv==0); }
    else if (wv<8){ mvOn=true;dtv=1;kqi=wv-4;comb=(wv==4);wPIH=(wv>4);
               wmat=Wih+(size_t)bt*H*H; }
    else if (wv==8){ isStg=true; }
  }

  const int koffT[4]={0,24,52,76}, klenT[4]={24,28,24,24};
  const int q = isOut ? (lane<40 ? lane/10 : 3) : kqi;
  const int koffv=koffT[q], klenv=klenT[q];
  const int r0 = isOut ? (lane<40 ? (lane - (lane/10)*10) : H) : 2*lane;
  const int r1 = isOut ? H : 2*lane+1;
  const int r0c=(r0<H)?r0:0, r1c=(r1<H)?r1:0;
  const float mA=(mvOn && r0<H)?1.f:0.f;
  const float mB=(mvOn && r1<H)?1.f:0.f;

  // ---- weights: 2 rows x up to 14 f32x2 (masked loads) ---------------------
  f32x2 z2; z2.x=0.f; z2.y=0.f;
  f32x2 WA0=z2,WA1=z2,WA2=z2,WA3=z2,WA4=z2,WA5=z2,WA6=z2,WA7=z2,WA8=z2,
        WA9=z2,WA10=z2,WA11=z2,WA12=z2,WA13=z2;
  f32x2 WB0=z2,WB1=z2,WB2=z2,WB3=z2,WB4=z2,WB5=z2,WB6=z2,WB7=z2,WB8=z2,
        WB9=z2,WB10=z2,WB11=z2,WB12=z2,WB13=z2;
#define LW(J,WAJ,WBJ) { const int off=koffv+2*(J); const int offc=(off<=98)?off:96; \
  const float mj=((2*(J))<klenv)?1.f:0.f; const float ma=mA*mj, mb=mB*mj; \
  f32x2 la=*(const f32x2*)(wmat+(size_t)r0c*H+offc); \
  f32x2 lb=*(const f32x2*)(wmat+(size_t)r1c*H+offc); \
  WAJ.x=la.x*ma; WAJ.y=la.y*ma; WBJ.x=lb.x*mb; WBJ.y=lb.y*mb; }
  LW(0,WA0,WB0)  LW(1,WA1,WB1)  LW(2,WA2,WB2)  LW(3,WA3,WB3)
  LW(4,WA4,WB4)  LW(5,WA5,WB5)  LW(6,WA6,WB6)  LW(7,WA7,WB7)
  LW(8,WA8,WB8)  LW(9,WA9,WB9)  LW(10,WA10,WB10) LW(11,WA11,WB11)
  LW(12,WA12,WB12) LW(13,WA13,WB13)
#undef LW

  f32x2 XA0=z2,XA1=z2,XB0=z2,XB1=z2;
  int xo=0;
  if (hasX){
    const int xoT[4]={0,4,8,8}, xlT[4]={4,4,2,0};
    xo=xoT[kqi]; const int xl=xlT[kqi];
    { const int c=xo;   const int cc=(c<=8)?c:8; const float mj=(0<xl)?1.f:0.f;
      f32x2 la=*(const f32x2*)(Wih0+(size_t)r0c*NIN+cc);
      f32x2 lb=*(const f32x2*)(Wih0+(size_t)r1c*NIN+cc);
      XA0.x=la.x*(mA*mj); XA0.y=la.y*(mA*mj);
      XB0.x=lb.x*(mB*mj); XB0.y=lb.y*(mB*mj); }
    { const int c=xo+2; const int cc=(c<=8)?c:8; const float mj=(2<xl)?1.f:0.f;
      f32x2 la=*(const f32x2*)(Wih0+(size_t)r0c*NIN+cc);
      f32x2 lb=*(const f32x2*)(Wih0+(size_t)r1c*NIN+cc);
      XA1.x=la.x*(mA*mj); XA1.y=la.y*(mA*mj);
      XB1.x=lb.x*(mB*mj); XB1.y=lb.y*(mB*mj); }
  }

  f32x2 biasP=z2;
  if (finalz){
    if (r0<H) biasP.x = bih[layerHH*H+r0]+bhh[layerHH*H+r0];
    if (r1<H) biasP.y = bih[layerHH*H+r1]+bhh[layerHH*H+r1];
  }
  float boutv=0.f;
  if (isOut && lane<OUTN) boutv = bout[lane];   // hoisted: no in-loop global

  asm volatile("" : "+v"(WA0),"+v"(WA1),"+v"(WA2),"+v"(WA3),"+v"(WA4),
                    "+v"(WA5),"+v"(WA6),"+v"(WA7));
  asm volatile("" : "+v"(WA8),"+v"(WA9),"+v"(WA10),"+v"(WA11),"+v"(WA12),
                    "+v"(WA13),"+v"(XA0),"+v"(XA1));
  asm volatile("" : "+v"(WB0),"+v"(WB1),"+v"(WB2),"+v"(WB3),"+v"(WB4),
                    "+v"(WB5),"+v"(WB6),"+v"(WB7));
  asm volatile("" : "+v"(WB8),"+v"(WB9),"+v"(WB10),"+v"(WB11),"+v"(WB12),
                    "+v"(WB13),"+v"(XB0),"+v"(XB1));

  // ---- flags / ring bases --------------------------------------------------
  int* progp=nullptr; int* consp=nullptr; int* progc=nullptr; int* consc=nullptr;
  if (bt<3){ progp=flags+(bt*NB+b)*32;     consp=flags+((3+bt)*NB+b)*32; }
  if (bt>0){ progc=flags+((bt-1)*NB+b)*32; consc=flags+((3+bt-1)*NB+b)*32; }
  const size_t rbW=(size_t)(bt*NB+b)*slots*100;
  const size_t rbR=(size_t)(((bt>0?bt:1)-1)*NB+b)*slots*25;

  // ---- LDS init ------------------------------------------------------------
  if (tid<128){ int r=tid; hbA[0][r]=0.f; float v=0.f;
    if (r<H) v=hprev[((size_t)bt*NB+b)*H+r];
    hbA[1][r]=v; }
  else if (tid<256){ int r=tid-128; hbB[0][r]=0.f; float v=0.f;
    if (bt==3 && r<H) v=hprev[((size_t)4*NB+b)*H+r];
    hbB[1][r]=v; }
  if (xStg){                      // zero pads + pre-stage x rows 0..31
    for (int i=lane;i<4*KB;i+=64){ xs[i>>4][i&15][10]=0.f; xs[i>>4][i&15][11]=0.f; }
    const f32x2* xg2=(const f32x2*)(xg+(size_t)b*T*NIN);
    for (int i=lane;i<32*5;i+=64){ int row=i/5,c=i-row*5;
      *(f32x2*)&xs[(row>>4)&3][row&15][2*c] = xg2[(size_t)row*5+c]; }
  }
  if (isStg){                     // pre-stage ring batches [0..31]
    while (__hip_atomic_load(progc,__ATOMIC_RELAXED,__HIP_MEMORY_SCOPE_AGENT)<2*KB)
      __builtin_amdgcn_s_sleep(1);
    (void)__hip_atomic_load(progc,__ATOMIC_ACQUIRE,__HIP_MEMORY_SCOPE_AGENT);
    const float4* r4=(const float4*)ring;
    float4* d4=(float4*)sIn;
    for (int i=lane;i<2*KB*25;i+=64){ int sl=i/25, off=i-sl*25;
      d4[sl*32+off]=r4[rbR+(size_t)(sl&sm1)*25+off]; }
    if (lane==0)
      __hip_atomic_store(consc,2*KB,__ATOMIC_RELEASE,__HIP_MEMORY_SCOPE_AGENT);
  }
  __syncthreads();

  // ---- main loop -----------------------------------------------------------
  float y0=0,y1=0,y2=0,y3=0,y4=0,y5=0,y6=0,y7=0;
  f32x2 rb0=z2,rb1=z2,rb2=z2,rb3=z2,rb4=z2,rb5=z2,rb6=z2,rb7=z2;
  const size_t yB=(size_t)b*T*OUTN, hfB=(size_t)NB*T*OUTN;

  for (int s=0; s<=T+2; ++s){
    const int t=s-dtv;
    const bool act = ((unsigned)t < (unsigned)T);
    float aA=0.f, aB=0.f;

    if (comb && act && (t&(KB-1))==0){       // backpressure (1/16)
      const int need = t + KB - slots;
      if (need>0){
        while (__hip_atomic_load(consp,__ATOMIC_RELAXED,__HIP_MEMORY_SCOPE_AGENT)<need)
          __builtin_amdgcn_s_sleep(1);
        (void)__hip_atomic_load(consp,__ATOMIC_ACQUIRE,__HIP_MEMORY_SCOPE_AGENT);
      }
    }

    if (act && mvOn){
      const int sl=(t&1)^(isHH?1:0);
      const float4* h4=(const float4*)((useB?hbB[sl]:hbA[sl])+koffv);
      f32x2 accA=z2, accB=z2;
#define MVQ(J,wa0,wa1,wb0,wb1) { float4 hv=h4[J]; \
      f32x2 p0; p0.x=hv.x; p0.y=hv.y; f32x2 p1; p1.x=hv.z; p1.y=hv.w; \
      asm("v_pk_fma_f32 %0, %1, %2, %0":"+v"(accA):"v"(wa0),"v"(p0)); \
      asm("v_pk_fma_f32 %0, %1, %2, %0":"+v"(accB):"v"(wb0),"v"(p0)); \
      asm("v_pk_fma_f32 %0, %1, %2, %0":"+v"(accA):"v"(wa1),"v"(p1)); \
      asm("v_pk_fma_f32 %0, %1, %2, %0":"+v"(accB):"v"(wb1),"v"(p1)); }
      MVQ(0,WA0,WA1,WB0,WB1)   MVQ(1,WA2,WA3,WB2,WB3)
      MVQ(2,WA4,WA5,WB4,WB5)   MVQ(3,WA6,WA7,WB6,WB7)
      MVQ(4,WA8,WA9,WB8,WB9)   MVQ(5,WA10,WA11,WB10,WB11)
      MVQ(6,WA12,WA13,WB12,WB13)
#undef MVQ
      if (hasX){
        float4 xv=*(const float4*)(xs[(t>>4)&3][t&15]+xo);
        f32x2 p0; p0.x=xv.x; p0.y=xv.y; f32x2 p1; p1.x=xv.z; p1.y=xv.w;
        asm("v_pk_fma_f32 %0, %1, %2, %0":"+v"(accA):"v"(XA0),"v"(p0));
        asm("v_pk_fma_f32 %0, %1, %2, %0":"+v"(accB):"v"(XB0),"v"(p0));
        asm("v_pk_fma_f32 %0, %1, %2, %0":"+v"(accA):"v"(XA1),"v"(p1));
        asm("v_pk_fma_f32 %0, %1, %2, %0":"+v"(accB):"v"(XB1),"v"(p1));
      }
      aA=accA.x+accA.y; aB=accB.x+accB.y;
      if (wPHH){ f32x2 st; st.x=aA; st.y=aB;
        *(f32x2*)&partHH[roleIdx][kqi-1][2*lane]=st; }
      if (wPIH){ f32x2 st; st.x=aA; st.y=aB;
        *(f32x2*)&partIH[t&1][kqi][2*lane]=st; }
    }

    if (isStg && (s&(KB-1))==(KB-1)){        // lookahead ring staging (1/16)
      const int m=s+17;                      // m = multiple of 16
      if (m+KB<=T){
        const int target=m+KB;
        while (__hip_atomic_load(progc,__ATOMIC_RELAXED,__HIP_MEMORY_SCOPE_AGENT)<target)
          __builtin_amdgcn_s_sleep(1);
        (void)__hip_atomic_load(progc,__ATOMIC_ACQUIRE,__HIP_MEMORY_SCOPE_AGENT);
        const float4* r4=(const float4*)ring;
        float4* d4=(float4*)sIn;
        const int bb=((m>>4)&3)*KB;
        for (int i=lane;i<KB*25;i+=64){ int sl=i/25, off=i-sl*25;
          d4[(bb+sl)*32+off]=r4[rbR+(size_t)((m+sl)&sm1)*25+off]; }
        if (lane==0)
          __hip_atomic_store(consc,target,__ATOMIC_RELEASE,__HIP_MEMORY_SCOPE_AGENT);
      }
    }
    if (xStg && (s&(KB-1))==(KB-1)){         // lookahead x staging (1/16)
      const int m=s+17;
      if (m+KB<=T){
        const f32x2* xg2=(const f32x2*)(xg+(size_t)b*T*NIN);
        const int bb=(m>>4)&3;
        for (int i=lane;i<KB*5;i+=64){ int row=i/5,c=i-row*5;
          *(f32x2*)&xs[bb][row][2*c] = xg2[(size_t)(m+row)*5+c]; }
      }
    }
    __syncthreads();

    // ---- phase 2 -----------------------------------------------------------
    if (act && finalz){
      f32x2 v; v.x=aA+biasP.x; v.y=aB+biasP.y;
      { f32x2 p=*(const f32x2*)&partHH[roleIdx][0][2*lane]; v.x+=p.x; v.y+=p.y; }
      { f32x2 p=*(const f32x2*)&partHH[roleIdx][1][2*lane]; v.x+=p.x; v.y+=p.y; }
      { f32x2 p=*(const f32x2*)&partHH[roleIdx][2][2*lane]; v.x+=p.x; v.y+=p.y; }
      if (inSIn){ f32x2 p=*(const f32x2*)&sIn[(t>>4)&3][t&15][2*lane];
        v.x+=p.x; v.y+=p.y; }
      if (inPIH){
        { f32x2 p=*(const f32x2*)&partIH[t&1][0][2*lane]; v.x+=p.x; v.y+=p.y; }
        { f32x2 p=*(const f32x2*)&partIH[t&1][1][2*lane]; v.x+=p.x; v.y+=p.y; }
        { f32x2 p=*(const f32x2*)&partIH[t&1][2][2*lane]; v.x+=p.x; v.y+=p.y; }
        { f32x2 p=*(const f32x2*)&partIH[t&1][3][2*lane]; v.x+=p.x; v.y+=p.y; }
      }
      const float h0v=ftanh(v.x), h1v=ftanh(v.y);
      if (r0<H){
        f32x2 st; st.x=h0v; st.y=h1v;
        *(f32x2*)&((wrB?hbB:hbA)[t&1][2*lane])=st;
        if (t==T-1)
          *(f32x2*)&outf[hfB+((size_t)layerHH*NB+b)*H+r0]=st;
      }
    }
    if (act && comb){
      f32x2 v; v.x=aA; v.y=aB;
      { f32x2 p=*(const f32x2*)&partIH[t&1][1][2*lane]; v.x+=p.x; v.y+=p.y; }
      { f32x2 p=*(const f32x2*)&partIH[t&1][2][2*lane]; v.x+=p.x; v.y+=p.y; }
      { f32x2 p=*(const f32x2*)&partIH[t&1][3][2*lane]; v.x+=p.x; v.y+=p.y; }
      const int ph=t&7;                      // 8-step batch in named regs
      rb0=(ph==0)?v:rb0; rb1=(ph==1)?v:rb1; rb2=(ph==2)?v:rb2; rb3=(ph==3)?v:rb3;
      rb4=(ph==4)?v:rb4; rb5=(ph==5)?v:rb5; rb6=(ph==6)?v:rb6; rb7=(ph==7)?v:rb7;
      if (ph==7 && r0<H){                    // flush slots t-7..t (1/8 steps)
        *(f32x2*)&ring[rbW+(size_t)((t-7)&sm1)*100+r0]=rb0;
        *(f32x2*)&ring[rbW+(size_t)((t-6)&sm1)*100+r0]=rb1;
        *(f32x2*)&ring[rbW+(size_t)((t-5)&sm1)*100+r0]=rb2;
        *(f32x2*)&ring[rbW+(size_t)((t-4)&sm1)*100+r0]=rb3;
        *(f32x2*)&ring[rbW+(size_t)((t-3)&sm1)*100+r0]=rb4;
        *(f32x2*)&ring[rbW+(size_t)((t-2)&sm1)*100+r0]=rb5;
        *(f32x2*)&ring[rbW+(size_t)((t-1)&sm1)*100+r0]=rb6;
        *(f32x2*)&ring[rbW+(size_t)( t   &sm1)*100+r0]=rb7;
      }
      if ((t&15)==15 && lane==0)
        __hip_atomic_store(progp,t+1,__ATOMIC_RELEASE,__HIP_MEMORY_SCOPE_AGENT);
    }
    if (act && isOut){
      float a2=aA+__shfl_down(aA,20,64);
      float yv=a2+__shfl_down(a2,10,64);
      if (lane<OUTN){
        yv += boutv;
        const int ph=t&7;
        y0=(ph==0)?yv:y0; y1=(ph==1)?yv:y1; y2=(ph==2)?yv:y2; y3=(ph==3)?yv:y3;
        y4=(ph==4)?yv:y4; y5=(ph==5)?yv:y5; y6=(ph==6)?yv:y6; y7=(ph==7)?yv:y7;
        if (ph==7){
          const size_t bi=yB+(size_t)(t-7)*OUTN+lane;
          outf[bi+0*OUTN]=y0; outf[bi+1*OUTN]=y1; outf[bi+2*OUTN]=y2;
          outf[bi+3*OUTN]=y3; outf[bi+4*OUTN]=y4; outf[bi+5*OUTN]=y5;
          outf[bi+6*OUTN]=y6; outf[bi+7*OUTN]=y7;
        }
      }
    }
    __syncthreads();
  }
  if (comb && lane==0)
    __hip_atomic_store(progp,T,__ATOMIC_RELEASE,__HIP_MEMORY_SCOPE_AGENT);
}

extern "C" void kernel_launch(void* const* d_in, const int* in_sizes, int n_in,
                              void* d_out, int out_size, void* d_ws, size_t ws_size,
                              hipStream_t stream){
  int* flags=(int*)d_ws;                     // 6*64*32 ints; 0xAA poison < 0
  size_t flagBytes=(size_t)6*NB*32*sizeof(int);
  float* ring=(float*)((char*)d_ws+flagBytes);
  size_t availF = ws_size>flagBytes ? (ws_size-flagBytes)/sizeof(float) : 0;
  int slots=64;
  while (slots>32 && (size_t)3*NB*slots*100 > availF) slots>>=1;
  rnn5<<<dim3(256), dim3(896), 0, stream>>>(
    (const float*)d_in[0], (const float*)d_in[1], (const float*)d_in[2],
    (const float*)d_in[3], (const float*)d_in[4], (const float*)d_in[5],
    (const float*)d_in[6], (const float*)d_in[7], (const float*)d_in[8],
    (float*)d_out, ring, flags, slots);
}